// Round 9
// baseline (655.077 us; speedup 1.0000x reference)
//
#include <hip/hip_runtime.h>
#include <hip/hip_bf16.h>
#include <math.h>

#define INPUT 2048
#define HIDDEN 128
#define BATCH 64
#define TSTEPS 512
#define KSLICE 4
#define KS (INPUT / KSLICE)   // 512
#define SNKT (KS / 64)        // 8 K-tiles of 64 per slice
#define RB 16                 // batch rows per rec block

typedef _Float16 half_t;
typedef __attribute__((ext_vector_type(2))) _Float16 half2_t;
typedef __attribute__((ext_vector_type(8))) _Float16 f16x8;
typedef __attribute__((ext_vector_type(4))) float f32x4;

static __device__ __forceinline__ f16x8 as_f16x8(uint4 v) {
  return __builtin_bit_cast(f16x8, v);
}
static __device__ __forceinline__ unsigned int h2u(half2_t v) {
  return __builtin_bit_cast(unsigned int, v);
}
static __device__ __forceinline__ half2_t pkrtz(float a, float b) {
  return __builtin_bit_cast(half2_t, __builtin_amdgcn_cvt_pkrtz(a, b));
}
static __device__ __forceinline__ float h2f(unsigned short u) {
  return (float)__builtin_bit_cast(half_t, u);
}

// tanh(x) = 1 - 2/(e^{2x}+1); e^{2x} = 2^{x*2/ln2}. Saturates correctly.
static __device__ __forceinline__ float tanh_fast(float x) {
#if __has_builtin(__builtin_amdgcn_exp2f)
  const float e = __builtin_amdgcn_exp2f(x * 2.885390082f);
#else
  const float e = exp2f(x * 2.885390082f);
#endif
  return 1.f - 2.f * __builtin_amdgcn_rcpf(e + 1.f);
}

// ---------------------------------------------------------------------------
// Fused producer/consumer kernel.
//   blocks 0..3     : recurrence, 16 batch rows each (dispatched FIRST so they
//                     are resident before producers fill the machine).
//   blocks 4..2051  : GEMM producers, one per (t, k-slice):
//                     t = (bid-4)>>2, s = (bid-4)&3.  Each computes
//                     partial xw[b=0..63][t][0..127] over k in [s*512,(s+1)*512)
//                     and accumulates into f16 xw serialized by flag[t] chain
//                     (deterministic: slice order is fixed).
// LDS padded to 84 KiB -> exactly 1 block/CU: rec CUs are exclusive, and the
// 2048 producers run in ~8 dispatch rounds, so low-t blocks COMPLETE first
// (early availability for the consumer instead of everything at once).
// ---------------------------------------------------------------------------
__global__ __launch_bounds__(256) void fused_kernel(
    const float* __restrict__ x, const float* __restrict__ W_ih,
    const float* __restrict__ W_hh, const float* __restrict__ b_ih,
    const float* __restrict__ b_hh, const float* __restrict__ W_fc,
    const float* __restrict__ b_fc, half_t* __restrict__ xw,
    int* __restrict__ flags, float* __restrict__ out) {
  __shared__ __align__(16) char smem[86016];  // 84 KiB pad -> 1 block/CU

  const int tid = threadIdx.x;
  const int lane = tid & 63;
  const int w = tid >> 6;   // wave 0..3
  const int l15 = lane & 15;

  if (blockIdx.x >= 4) {
    // =================== producer: GEMM k-slice for one t ===================
    const int p = blockIdx.x - 4;
    const int t = p >> 2;
    const int s = p & 3;

    auto sA = (uint4(*)[8][64])smem;            // [2][8][64]  16 KB
    auto sB = (uint4(*)[8][128])(smem + 16384); // [2][8][128] 32 KB

    const int wr = w >> 1, wc = w & 1;
    const int kcl = lane >> 4;

    // staging maps
    const int xm = tid & 63, xkq = tid >> 6;   // x: batch row, k-quarter (16 f32)
    const int wn = tid & 127, wkh = tid >> 7;  // W: col, k-half (32 f32)
    const float* xsrc = x + ((size_t)xm * TSTEPS + t) * INPUT + s * KS + xkq * 16;
    const float* wsrc = W_ih + (size_t)wn * INPUT + s * KS + wkh * 32;

    f32x4 acc[2][4];
#pragma unroll
    for (int rt = 0; rt < 2; ++rt)
#pragma unroll
      for (int ct = 0; ct < 4; ++ct) acc[rt][ct] = (f32x4)0.f;

    float bias_c[4];
#pragma unroll
    for (int ct = 0; ct < 4; ++ct) {
      const int col = wc * 64 + ct * 16 + l15;
      bias_c[ct] = b_ih[col] + b_hh[col];
    }

    float4 xv[4], wv[8];
    auto LOADT = [&](int kt) {
      const float4* xs = (const float4*)(xsrc + kt * 64);
#pragma unroll
      for (int j = 0; j < 4; ++j) xv[j] = xs[j];
      const float4* wsp = (const float4*)(wsrc + kt * 64);
#pragma unroll
      for (int j = 0; j < 8; ++j) wv[j] = wsp[j];
    };
    auto WRITET = [&](int bf) {
#pragma unroll
      for (int gg = 0; gg < 2; ++gg) {
        uint4 q = {h2u(pkrtz(xv[2 * gg].x, xv[2 * gg].y)),
                   h2u(pkrtz(xv[2 * gg].z, xv[2 * gg].w)),
                   h2u(pkrtz(xv[2 * gg + 1].x, xv[2 * gg + 1].y)),
                   h2u(pkrtz(xv[2 * gg + 1].z, xv[2 * gg + 1].w))};
        sA[bf][xkq * 2 + gg][xm] = q;
      }
#pragma unroll
      for (int gg = 0; gg < 4; ++gg) {
        uint4 q = {h2u(pkrtz(wv[2 * gg].x, wv[2 * gg].y)),
                   h2u(pkrtz(wv[2 * gg].z, wv[2 * gg].w)),
                   h2u(pkrtz(wv[2 * gg + 1].x, wv[2 * gg + 1].y)),
                   h2u(pkrtz(wv[2 * gg + 1].z, wv[2 * gg + 1].w))};
        sB[bf][wkh * 4 + gg][wn] = q;
      }
    };

    LOADT(0);
    WRITET(0);
    __syncthreads();

    for (int kt = 0; kt < SNKT; ++kt) {
      const int pb = kt & 1;
      if (kt + 1 < SNKT) LOADT(kt + 1);

      uint4 af[2][2], bfr[2][4];
#pragma unroll
      for (int kf = 0; kf < 2; ++kf) {
#pragma unroll
        for (int rt = 0; rt < 2; ++rt)
          af[kf][rt] = sA[pb][kf * 4 + kcl][wr * 32 + rt * 16 + l15];
#pragma unroll
        for (int ct = 0; ct < 4; ++ct)
          bfr[kf][ct] = sB[pb][kf * 4 + kcl][wc * 64 + ct * 16 + l15];
      }
#pragma unroll
      for (int kf = 0; kf < 2; ++kf)
#pragma unroll
        for (int rt = 0; rt < 2; ++rt)
#pragma unroll
          for (int ct = 0; ct < 4; ++ct)
            acc[rt][ct] = __builtin_amdgcn_mfma_f32_16x16x32_f16(
                as_f16x8(af[kf][rt]), as_f16x8(bfr[kf][ct]), acc[rt][ct], 0, 0, 0);

      if (kt + 1 < SNKT) WRITET(pb ^ 1);
      __syncthreads();
    }

    // ---- serialized accumulate into f16 xw (slice order via flag chain)
    if (s != 0) {
      if (tid == 0)
        while (__hip_atomic_load(&flags[t], __ATOMIC_ACQUIRE,
                                 __HIP_MEMORY_SCOPE_AGENT) != s) {}
      __syncthreads();
    }
    const int rb2 = wr * 32 + (lane >> 4) * 4;  // batch-row base
#pragma unroll
    for (int rt = 0; rt < 2; ++rt)
#pragma unroll
      for (int ct = 0; ct < 4; ++ct) {
        const int col = wc * 64 + ct * 16 + l15;
#pragma unroll
        for (int j = 0; j < 4; ++j) {
          const int row = rb2 + rt * 16 + j;  // batch index 0..63
          const size_t idx = ((size_t)row * TSTEPS + t) * HIDDEN + col;
          if (s == 0) {
            xw[idx] = (half_t)(acc[rt][ct][j] + bias_c[ct]);
          } else {
            xw[idx] = (half_t)((float)xw[idx] + acc[rt][ct][j]);
          }
        }
      }
    __syncthreads();  // drains all waves' stores (vmcnt 0 before barrier)
    if (tid == 0)
      __hip_atomic_store(&flags[t], s + 1, __ATOMIC_RELEASE,
                         __HIP_MEMORY_SCOPE_AGENT);
    return;
  }

  // ======================= consumer: recurrence ============================
  const int blk = blockIdx.x;    // 0..3 -> batch quarter
  const int bl = lane & 15;      // batch-local 0..15
  const int g = lane >> 4;       // k-group 0..3
  const int swz = (bl & 7) << 4; // LDS XOR swizzle

  char* st0 = smem;              // state buffer 0 (4 KB)
  char* st1 = smem + 4096;       // state buffer 1
  float* red = (float*)(smem + 8192);

  // A-frags: W_hh rows (f32 -> f16 in reg, once). frag(mi,kt) =
  // W_hh[(2w+mi)*16+bl][kt*32+g*8 .. +7]
  uint4 afr[2][4];
#pragma unroll
  for (int mi = 0; mi < 2; ++mi)
#pragma unroll
    for (int kt = 0; kt < 4; ++kt) {
      const float* wr4 =
          W_hh + ((size_t)((2 * w + mi) * 16 + bl)) * HIDDEN + kt * 32 + g * 8;
      const float4 wa = ((const float4*)wr4)[0];
      const float4 wb = ((const float4*)wr4)[1];
      uint4 q = {h2u(pkrtz(wa.x, wa.y)), h2u(pkrtz(wa.z, wa.w)),
                 h2u(pkrtz(wb.x, wb.y)), h2u(pkrtz(wb.z, wb.w))};
      afr[mi][kt] = q;
    }

  // zero state[0]
#pragma unroll
  for (int i = 0; i < 4; ++i) ((unsigned int*)st0)[tid + 256 * i] = 0u;
  __syncthreads();

  const half_t* xb0 =
      xw + ((size_t)(blk * RB + bl) * TSTEPS) * HIDDEN + w * 32 + g * 4;
  const half_t* xb1 = xb0 + 16;

  float hh[2][4];

  auto aload = [&](int tt) {
    return __hip_atomic_load(&flags[tt], __ATOMIC_ACQUIRE,
                             __HIP_MEMORY_SCOPE_AGENT);
  };

  auto STEP = [&](const char* stR, char* stW, ushort4 xc0, ushort4 xc1) {
    uint4 bfr[4];
#pragma unroll
    for (int kt = 0; kt < 4; ++kt) {
      const int off = (bl * 256 + kt * 64 + g * 16) ^ swz;
      bfr[kt] = *(const uint4*)(stR + off);
    }
    f32x4 a0, a1, e0, e1;
    a0[0] = h2f(xc0.x); a0[1] = h2f(xc0.y); a0[2] = h2f(xc0.z); a0[3] = h2f(xc0.w);
    a1[0] = h2f(xc1.x); a1[1] = h2f(xc1.y); a1[2] = h2f(xc1.z); a1[3] = h2f(xc1.w);
    // 2+2 MFMA chains per tile (halves the serial MFMA latency), f32 combine
    a0 = __builtin_amdgcn_mfma_f32_16x16x32_f16(as_f16x8(afr[0][0]), as_f16x8(bfr[0]), a0, 0, 0, 0);
    a0 = __builtin_amdgcn_mfma_f32_16x16x32_f16(as_f16x8(afr[0][1]), as_f16x8(bfr[1]), a0, 0, 0, 0);
    e0 = __builtin_amdgcn_mfma_f32_16x16x32_f16(as_f16x8(afr[0][2]), as_f16x8(bfr[2]), (f32x4)0.f, 0, 0, 0);
    e0 = __builtin_amdgcn_mfma_f32_16x16x32_f16(as_f16x8(afr[0][3]), as_f16x8(bfr[3]), e0, 0, 0, 0);
    a1 = __builtin_amdgcn_mfma_f32_16x16x32_f16(as_f16x8(afr[1][0]), as_f16x8(bfr[0]), a1, 0, 0, 0);
    a1 = __builtin_amdgcn_mfma_f32_16x16x32_f16(as_f16x8(afr[1][1]), as_f16x8(bfr[1]), a1, 0, 0, 0);
    e1 = __builtin_amdgcn_mfma_f32_16x16x32_f16(as_f16x8(afr[1][2]), as_f16x8(bfr[2]), (f32x4)0.f, 0, 0, 0);
    e1 = __builtin_amdgcn_mfma_f32_16x16x32_f16(as_f16x8(afr[1][3]), as_f16x8(bfr[3]), e1, 0, 0, 0);
    a0 += e0;
    a1 += e1;
#pragma unroll
    for (int j = 0; j < 4; ++j) {
      hh[0][j] = tanh_fast(a0[j]);
      hh[1][j] = tanh_fast(a1[j]);
    }
    uint2 p0 = {h2u(pkrtz(hh[0][0], hh[0][1])), h2u(pkrtz(hh[0][2], hh[0][3]))};
    uint2 p1 = {h2u(pkrtz(hh[1][0], hh[1][1])), h2u(pkrtz(hh[1][2], hh[1][3]))};
    const int w0 = (bl * 256 + (2 * w + 0) * 32 + g * 8) ^ swz;
    const int w1 = (bl * 256 + (2 * w + 1) * 32 + g * 8) ^ swz;
    *(uint2*)(stW + w0) = p0;
    *(uint2*)(stW + w1) = p1;
    __syncthreads();
  };

  // prologue: wait for t=0,1 and load their xw
  while (aload(0) != KSLICE) {}
  ushort4 xA0 = *(const ushort4*)(xb0);
  ushort4 xA1 = *(const ushort4*)(xb1);
  while (aload(1) != KSLICE) {}
  ushort4 xB0 = *(const ushort4*)(xb0 + HIDDEN);
  ushort4 xB1 = *(const ushort4*)(xb1 + HIDDEN);

  for (int t2 = 0; t2 < TSTEPS; t2 += 2) {
    const ushort4 c0 = xA0, c1 = xA1;
    int f2 = (t2 + 2 < TSTEPS) ? aload(t2 + 2) : KSLICE;  // issued early
    STEP(st0, st1, c0, c1);  // even t: read st0, write st1
    if (t2 + 2 < TSTEPS) {
      while (f2 != KSLICE) f2 = aload(t2 + 2);
      xA0 = *(const ushort4*)(xb0 + (size_t)(t2 + 2) * HIDDEN);
      xA1 = *(const ushort4*)(xb1 + (size_t)(t2 + 2) * HIDDEN);
    }
    const ushort4 d0 = xB0, d1 = xB1;
    int f3 = (t2 + 3 < TSTEPS) ? aload(t2 + 3) : KSLICE;
    STEP(st1, st0, d0, d1);  // odd t: read st1, write st0
    if (t2 + 3 < TSTEPS) {
      while (f3 != KSLICE) f3 = aload(t2 + 3);
      xB0 = *(const ushort4*)(xb0 + (size_t)(t2 + 3) * HIDDEN);
      xB1 = *(const ushort4*)(xb1 + (size_t)(t2 + 3) * HIDDEN);
    }
  }

  // fused FC: out[b] = sum_{h'} h_last[b][h'] * W_fc[h'] + b_fc
  const float4 wf0 = *(const float4*)&W_fc[(2 * w + 0) * 16 + g * 4];
  const float4 wf1 = *(const float4*)&W_fc[(2 * w + 1) * 16 + g * 4];
  float partial = hh[0][0] * wf0.x + hh[0][1] * wf0.y + hh[0][2] * wf0.z +
                  hh[0][3] * wf0.w + hh[1][0] * wf1.x + hh[1][1] * wf1.y +
                  hh[1][2] * wf1.z + hh[1][3] * wf1.w;
  red[tid] = partial;
  __syncthreads();
  if (tid < RB) {
    float ssum = b_fc[0];
#pragma unroll
    for (int q = 0; q < 16; ++q) ssum += red[q * 16 + tid];
    out[blk * RB + tid] = ssum;
  }
}

extern "C" void kernel_launch(void* const* d_in, const int* in_sizes, int n_in,
                              void* d_out, int out_size, void* d_ws, size_t ws_size,
                              hipStream_t stream) {
  const float* x    = (const float*)d_in[0];
  const float* W_ih = (const float*)d_in[1];
  const float* W_hh = (const float*)d_in[2];
  const float* b_ih = (const float*)d_in[3];
  const float* b_hh = (const float*)d_in[4];
  const float* W_fc = (const float*)d_in[5];
  const float* b_fc = (const float*)d_in[6];

  char* ws = (char*)d_ws;
  int*    flags = (int*)ws;                 // 512 ints (+ pad to 4 KB)
  half_t* xwf16 = (half_t*)(ws + 4096);     // 8 MB

  // reset flags every launch (graph-capture-safe async memset)
  hipMemsetAsync(ws, 0, 4096, stream);

  fused_kernel<<<4 + TSTEPS * KSLICE, 256, 0, stream>>>(
      x, W_ih, W_hh, b_ih, b_hh, W_fc, b_fc, xwf16, flags, (float*)d_out);
}

// Round 10
// 283.579 us; speedup vs baseline: 2.3100x; 2.3100x over previous
//
#include <hip/hip_runtime.h>
#include <hip/hip_bf16.h>
#include <math.h>

#define INPUT 2048
#define HIDDEN 128
#define BATCH 64
#define TSTEPS 512
#define RB 16

typedef _Float16 half_t;
typedef __attribute__((ext_vector_type(2))) _Float16 half2_t;
typedef __attribute__((ext_vector_type(8))) _Float16 f16x8;
typedef __attribute__((ext_vector_type(4))) float f32x4;

static __device__ __forceinline__ f16x8 as_f16x8(uint4 v) {
  return __builtin_bit_cast(f16x8, v);
}
static __device__ __forceinline__ unsigned int h2u(half2_t v) {
  return __builtin_bit_cast(unsigned int, v);
}
static __device__ __forceinline__ half2_t pkrtz(float a, float b) {
  return __builtin_bit_cast(half2_t, __builtin_amdgcn_cvt_pkrtz(a, b));
}
static __device__ __forceinline__ float h2f(unsigned short u) {
  return (float)__builtin_bit_cast(half_t, u);
}

// tanh(x) = 1 - 2/(e^{2x}+1); e^{2x} = 2^{x*2/ln2}. Saturates correctly.
static __device__ __forceinline__ float tanh_fast(float x) {
#if __has_builtin(__builtin_amdgcn_exp2f)
  const float e = __builtin_amdgcn_exp2f(x * 2.885390082f);
#else
  const float e = exp2f(x * 2.885390082f);
#endif
  return 1.f - 2.f * __builtin_amdgcn_rcpf(e + 1.f);
}

// ---------------------------------------------------------------------------
// Prep: W_ih f32 -> Wg granule layout (Wg[kc*128+col] = uint4 of f16
// W_ih[col][kc*8..kc*8+7]) so GEMM B-frags load straight from L2, coalesced.
// W_hh f32 -> packed half2 (k-major) for the recurrence.
// ---------------------------------------------------------------------------
__global__ __launch_bounds__(256) void prep_kernel(
    const float* __restrict__ W_ih, const float* __restrict__ W_hh,
    uint4* __restrict__ Wg, unsigned int* __restrict__ Whh2) {
  const int id = blockIdx.x * 256 + threadIdx.x;  // 32768 threads
  const int col = id & 127;
  const int kc = id >> 7;  // 0..255
  const float4 a = *(const float4*)(W_ih + (size_t)col * INPUT + kc * 8);
  const float4 b = *(const float4*)(W_ih + (size_t)col * INPUT + kc * 8 + 4);
  uint4 q = {h2u(pkrtz(a.x, a.y)), h2u(pkrtz(a.z, a.w)),
             h2u(pkrtz(b.x, b.y)), h2u(pkrtz(b.z, b.w))};
  Wg[(size_t)kc * 128 + col] = q;
  if (id < 8192) {
    float2 p = ((const float2*)W_hh)[id];
    half_t ha = (half_t)p.x, hb = (half_t)p.y;
    Whh2[id] = (unsigned int)__builtin_bit_cast(unsigned short, ha) |
               ((unsigned int)__builtin_bit_cast(unsigned short, hb) << 16);
  }
}

// ---------------------------------------------------------------------------
// GEMM: xw[row][h] = x[row]·W_ih[h] + b_ih[h] + b_hh[h], stored f16.
// BM=64, BK=64, 256 thr (4 waves: 2 row-grp x 2 col-grp), 512 blocks.
// A (x): LDS-staged with f32->f16 convert, 16 KB double buffer, depth-2
// register prefetch (x loads for tile k+2 issued during tile k — covers
// ~900cy HBM latency with a full tile of compute+barrier).
// B (W): NO LDS — direct coalesced uint4 granule loads from L2-resident Wg,
// depth-1 register prefetch. Removes 32 KB LDS + all B staging traffic.
// ---------------------------------------------------------------------------
#define GBM 64
#define GBK 64
#define GNKT (INPUT / GBK)  // 32

__global__ __launch_bounds__(256) void gemm_xw_f16(
    const float* __restrict__ x, const uint4* __restrict__ Wg,
    const float* __restrict__ b_ih, const float* __restrict__ b_hh,
    half_t* __restrict__ xw) {
  __shared__ uint4 sA[2][8][64];  // [buf][kc][m]  16 KB

  const int tid = threadIdx.x;
  const int lane = tid & 63;
  const int w = tid >> 6;
  const int wr = w >> 1, wc = w & 1;
  const int block_row = blockIdx.x * GBM;
  const int kcl = lane >> 4;
  const int l15 = lane & 15;

  const int xm = tid & 63, xkq = tid >> 6;  // x: row, k-quarter (16 f32)
  const float* xsrc = x + (size_t)(block_row + xm) * INPUT + xkq * 16;

  f32x4 acc[2][4];
#pragma unroll
  for (int rt = 0; rt < 2; ++rt)
#pragma unroll
    for (int ct = 0; ct < 4; ++ct) acc[rt][ct] = (f32x4)0.f;

  float bias_c[4];
#pragma unroll
  for (int ct = 0; ct < 4; ++ct) {
    const int col = wc * 64 + ct * 16 + l15;
    bias_c[ct] = b_ih[col] + b_hh[col];
  }

  float4 xva[4], xvb[4];
  uint4 br0[8], br1[8];

  auto XLOAD = [&](int kt, float4* xv) {
    const float4* xs = (const float4*)(xsrc + kt * GBK);
#pragma unroll
    for (int j = 0; j < 4; ++j) xv[j] = xs[j];
  };
  auto XWRITE = [&](int bf, const float4* xv) {
#pragma unroll
    for (int g = 0; g < 2; ++g) {
      uint4 q = {h2u(pkrtz(xv[2 * g].x, xv[2 * g].y)),
                 h2u(pkrtz(xv[2 * g].z, xv[2 * g].w)),
                 h2u(pkrtz(xv[2 * g + 1].x, xv[2 * g + 1].y)),
                 h2u(pkrtz(xv[2 * g + 1].z, xv[2 * g + 1].w))};
      sA[bf][xkq * 2 + g][xm] = q;
    }
  };
  auto BLOAD = [&](int kt, uint4* bb) {
#pragma unroll
    for (int kf = 0; kf < 2; ++kf)
#pragma unroll
      for (int ct = 0; ct < 4; ++ct)
        bb[kf * 4 + ct] =
            Wg[(size_t)(kt * 8 + kf * 4 + kcl) * 128 + wc * 64 + ct * 16 + l15];
  };
  auto COMPUTE = [&](int bf, const uint4* bb) {
    uint4 af[2][2];
#pragma unroll
    for (int kf = 0; kf < 2; ++kf)
#pragma unroll
      for (int rt = 0; rt < 2; ++rt)
        af[kf][rt] = sA[bf][kf * 4 + kcl][wr * 32 + rt * 16 + l15];
#pragma unroll
    for (int kf = 0; kf < 2; ++kf)
#pragma unroll
      for (int rt = 0; rt < 2; ++rt)
#pragma unroll
        for (int ct = 0; ct < 4; ++ct)
          acc[rt][ct] = __builtin_amdgcn_mfma_f32_16x16x32_f16(
              as_f16x8(af[kf][rt]), as_f16x8(bb[kf * 4 + ct]), acc[rt][ct], 0, 0, 0);
  };

  // prologue: x depth-2, B depth-1
  XLOAD(0, xva);
  XLOAD(1, xvb);
  BLOAD(0, br0);
  XWRITE(0, xva);
  __syncthreads();

#pragma unroll 1
  for (int kt = 0; kt < GNKT; kt += 2) {
    // even tile kt: buf 0, B in br0
    BLOAD(kt + 1, br1);
    if (kt + 2 < GNKT) XLOAD(kt + 2, xva);
    COMPUTE(0, br0);
    XWRITE(1, xvb);
    __syncthreads();
    // odd tile kt+1: buf 1, B in br1
    if (kt + 2 < GNKT) BLOAD(kt + 2, br0);
    if (kt + 3 < GNKT) XLOAD(kt + 3, xvb);
    COMPUTE(1, br1);
    if (kt + 2 < GNKT) {
      XWRITE(0, xva);
      __syncthreads();
    }
  }

  // epilogue: C layout col = lane&15, row = (lane>>4)*4 + j
  const int rbase = block_row + wr * 32 + (lane >> 4) * 4;
#pragma unroll
  for (int rt = 0; rt < 2; ++rt)
#pragma unroll
    for (int ct = 0; ct < 4; ++ct) {
      const int col = wc * 64 + ct * 16 + l15;
#pragma unroll
      for (int j = 0; j < 4; ++j) {
        const int row = rbase + rt * 16 + j;
        xw[(size_t)row * HIDDEN + col] = (half_t)(acc[rt][ct][j] + bias_c[ct]);
      }
    }
}

// ---------------------------------------------------------------------------
// Recurrence via MFMA (R8 structure, verified 186 us) + 2+2 MFMA split.
// 4 blocks x 16 batch rows, 256 threads. A = W_hh resident in VGPRs,
// B = h-state in LDS [batch][k] f16 with XOR swizzle, C-input = xw (folds
// the add), D writes back as contiguous b64. One barrier per step.
// ---------------------------------------------------------------------------
__global__ __launch_bounds__(256) void rnn_rec_mfma(
    const half_t* __restrict__ xw, const unsigned int* __restrict__ Whh2,
    const float* __restrict__ W_fc, const float* __restrict__ b_fc,
    float* __restrict__ out) {
  const int blk = blockIdx.x;    // 0..3
  const int tid = threadIdx.x;
  const int lane = tid & 63;
  const int w = tid >> 6;        // wave 0..3 -> h' tiles 2w, 2w+1
  const int bl = lane & 15;      // batch-local 0..15
  const int g = lane >> 4;       // k-group 0..3
  const int swz = (bl & 7) << 4; // LDS XOR swizzle (bits 4..6)

  __shared__ half_t st[2][RB][HIDDEN];  // 8 KB state double buffer
  __shared__ float red[256];

  uint4 afr[2][4];
#pragma unroll
  for (int mi = 0; mi < 2; ++mi)
#pragma unroll
    for (int kt = 0; kt < 4; ++kt)
      afr[mi][kt] = *(const uint4*)(Whh2 + ((size_t)((2 * w + mi) * 16 + bl)) * 64 +
                                    kt * 16 + g * 4);

#pragma unroll
  for (int i = 0; i < 4; ++i) ((unsigned int*)st)[tid + 256 * i] = 0u;
  __syncthreads();

  const half_t* xb0 = xw + ((size_t)(blk * RB + bl) * TSTEPS) * HIDDEN + w * 32 + g * 4;
  const half_t* xb1 = xb0 + 16;

  float hh[2][4];

  auto STEP = [&](const half_t* stR, half_t* stW, ushort4 xc0, ushort4 xc1) {
    uint4 bfr[4];
#pragma unroll
    for (int kt = 0; kt < 4; ++kt) {
      const int off = (bl * 256 + kt * 64 + g * 16) ^ swz;
      bfr[kt] = *(const uint4*)((const char*)stR + off);
    }
    f32x4 a0, a1, e0, e1;
    a0[0] = h2f(xc0.x); a0[1] = h2f(xc0.y); a0[2] = h2f(xc0.z); a0[3] = h2f(xc0.w);
    a1[0] = h2f(xc1.x); a1[1] = h2f(xc1.y); a1[2] = h2f(xc1.z); a1[3] = h2f(xc1.w);
    a0 = __builtin_amdgcn_mfma_f32_16x16x32_f16(as_f16x8(afr[0][0]), as_f16x8(bfr[0]), a0, 0, 0, 0);
    a0 = __builtin_amdgcn_mfma_f32_16x16x32_f16(as_f16x8(afr[0][1]), as_f16x8(bfr[1]), a0, 0, 0, 0);
    e0 = __builtin_amdgcn_mfma_f32_16x16x32_f16(as_f16x8(afr[0][2]), as_f16x8(bfr[2]), (f32x4)0.f, 0, 0, 0);
    e0 = __builtin_amdgcn_mfma_f32_16x16x32_f16(as_f16x8(afr[0][3]), as_f16x8(bfr[3]), e0, 0, 0, 0);
    a1 = __builtin_amdgcn_mfma_f32_16x16x32_f16(as_f16x8(afr[1][0]), as_f16x8(bfr[0]), a1, 0, 0, 0);
    a1 = __builtin_amdgcn_mfma_f32_16x16x32_f16(as_f16x8(afr[1][1]), as_f16x8(bfr[1]), a1, 0, 0, 0);
    e1 = __builtin_amdgcn_mfma_f32_16x16x32_f16(as_f16x8(afr[1][2]), as_f16x8(bfr[2]), (f32x4)0.f, 0, 0, 0);
    e1 = __builtin_amdgcn_mfma_f32_16x16x32_f16(as_f16x8(afr[1][3]), as_f16x8(bfr[3]), e1, 0, 0, 0);
    a0 += e0;
    a1 += e1;
#pragma unroll
    for (int j = 0; j < 4; ++j) {
      hh[0][j] = tanh_fast(a0[j]);
      hh[1][j] = tanh_fast(a1[j]);
    }
    uint2 p0 = {h2u(pkrtz(hh[0][0], hh[0][1])), h2u(pkrtz(hh[0][2], hh[0][3]))};
    uint2 p1 = {h2u(pkrtz(hh[1][0], hh[1][1])), h2u(pkrtz(hh[1][2], hh[1][3]))};
    const int w0 = (bl * 256 + (2 * w + 0) * 32 + g * 8) ^ swz;
    const int w1 = (bl * 256 + (2 * w + 1) * 32 + g * 8) ^ swz;
    *(uint2*)((char*)stW + w0) = p0;
    *(uint2*)((char*)stW + w1) = p1;
    __syncthreads();
  };

  ushort4 xA0 = *(const ushort4*)(xb0);
  ushort4 xA1 = *(const ushort4*)(xb1);
  ushort4 xB0 = *(const ushort4*)(xb0 + HIDDEN);
  ushort4 xB1 = *(const ushort4*)(xb1 + HIDDEN);

  for (int t2 = 0; t2 < TSTEPS; t2 += 2) {
    ushort4 c0 = xA0, c1 = xA1;
    xA0 = *(const ushort4*)(xb0 + (size_t)(t2 + 2) * HIDDEN);
    xA1 = *(const ushort4*)(xb1 + (size_t)(t2 + 2) * HIDDEN);
    STEP(&st[0][0][0], &st[1][0][0], c0, c1);

    ushort4 d0 = xB0, d1 = xB1;
    xB0 = *(const ushort4*)(xb0 + (size_t)(t2 + 3) * HIDDEN);
    xB1 = *(const ushort4*)(xb1 + (size_t)(t2 + 3) * HIDDEN);
    STEP(&st[1][0][0], &st[0][0][0], d0, d1);
  }

  const float4 wf0 = *(const float4*)&W_fc[(2 * w + 0) * 16 + g * 4];
  const float4 wf1 = *(const float4*)&W_fc[(2 * w + 1) * 16 + g * 4];
  float partial = hh[0][0] * wf0.x + hh[0][1] * wf0.y + hh[0][2] * wf0.z +
                  hh[0][3] * wf0.w + hh[1][0] * wf1.x + hh[1][1] * wf1.y +
                  hh[1][2] * wf1.z + hh[1][3] * wf1.w;
  red[tid] = partial;
  __syncthreads();
  if (tid < RB) {
    float s = b_fc[0];
#pragma unroll
    for (int q = 0; q < 16; ++q) s += red[q * 16 + tid];
    out[blk * RB + tid] = s;
  }
}

extern "C" void kernel_launch(void* const* d_in, const int* in_sizes, int n_in,
                              void* d_out, int out_size, void* d_ws, size_t ws_size,
                              hipStream_t stream) {
  const float* x    = (const float*)d_in[0];
  const float* W_ih = (const float*)d_in[1];
  const float* W_hh = (const float*)d_in[2];
  const float* b_ih = (const float*)d_in[3];
  const float* b_hh = (const float*)d_in[4];
  const float* W_fc = (const float*)d_in[5];
  const float* b_fc = (const float*)d_in[6];

  char* ws = (char*)d_ws;
  half_t*       xwf16 = (half_t*)ws;                                     // 8 MB
  uint4*        Wg    = (uint4*)(ws + (8u << 20));                       // 512 KB
  unsigned int* Whh2  = (unsigned int*)(ws + (8u << 20) + (512u << 10)); // 32 KB

  prep_kernel<<<128, 256, 0, stream>>>(W_ih, W_hh, Wg, Whh2);
  gemm_xw_f16<<<(BATCH * TSTEPS) / GBM, 256, 0, stream>>>(x, Wg, b_ih, b_hh, xwf16);
  rnn_rec_mfma<<<BATCH / RB, 256, 0, stream>>>(xwf16, Whh2, W_fc, b_fc, (float*)d_out);
}

// Round 11
// 259.239 us; speedup vs baseline: 2.5269x; 1.0939x over previous
//
#include <hip/hip_runtime.h>
#include <hip/hip_bf16.h>
#include <math.h>

#define INPUT 2048
#define HIDDEN 128
#define BATCH 64
#define TSTEPS 512
#define RB 16

typedef _Float16 half_t;
typedef __attribute__((ext_vector_type(2))) _Float16 half2_t;
typedef __attribute__((ext_vector_type(8))) _Float16 f16x8;
typedef __attribute__((ext_vector_type(4))) float f32x4;

static __device__ __forceinline__ f16x8 as_f16x8(uint4 v) {
  return __builtin_bit_cast(f16x8, v);
}
static __device__ __forceinline__ unsigned int h2u(half2_t v) {
  return __builtin_bit_cast(unsigned int, v);
}
static __device__ __forceinline__ half2_t pkrtz(float a, float b) {
  return __builtin_bit_cast(half2_t, __builtin_amdgcn_cvt_pkrtz(a, b));
}
static __device__ __forceinline__ float h2f(unsigned short u) {
  return (float)__builtin_bit_cast(half_t, u);
}

// tanh(x) = 1 - 2/(e^{2x}+1); e^{2x} = 2^{x*2/ln2}. Saturates correctly.
static __device__ __forceinline__ float tanh_fast(float x) {
#if __has_builtin(__builtin_amdgcn_exp2f)
  const float e = __builtin_amdgcn_exp2f(x * 2.885390082f);
#else
  const float e = exp2f(x * 2.885390082f);
#endif
  return 1.f - 2.f * __builtin_amdgcn_rcpf(e + 1.f);
}

// ---------------------------------------------------------------------------
// Prep: W_ih f32 -> Wg granule layout (Wg[kc*128+col] = uint4 of f16
// W_ih[col][kc*8..kc*8+7]) so GEMM B-frags load straight from L2, coalesced.
// W_hh f32 -> packed half2 (k-major) for the recurrence.
// ---------------------------------------------------------------------------
__global__ __launch_bounds__(256) void prep_kernel(
    const float* __restrict__ W_ih, const float* __restrict__ W_hh,
    uint4* __restrict__ Wg, unsigned int* __restrict__ Whh2) {
  const int id = blockIdx.x * 256 + threadIdx.x;  // 32768 threads
  const int col = id & 127;
  const int kc = id >> 7;  // 0..255
  const float4 a = *(const float4*)(W_ih + (size_t)col * INPUT + kc * 8);
  const float4 b = *(const float4*)(W_ih + (size_t)col * INPUT + kc * 8 + 4);
  uint4 q = {h2u(pkrtz(a.x, a.y)), h2u(pkrtz(a.z, a.w)),
             h2u(pkrtz(b.x, b.y)), h2u(pkrtz(b.z, b.w))};
  Wg[(size_t)kc * 128 + col] = q;
  if (id < 8192) {
    float2 p = ((const float2*)W_hh)[id];
    half_t ha = (half_t)p.x, hb = (half_t)p.y;
    Whh2[id] = (unsigned int)__builtin_bit_cast(unsigned short, ha) |
               ((unsigned int)__builtin_bit_cast(unsigned short, hb) << 16);
  }
}

// ---------------------------------------------------------------------------
// GEMM: xw[row][h] = x[row]·W_ih[h] + b_ih[h] + b_hh[h], stored f16.
// (R10 form, measured ~70 us / ~3.8 TB/s on x.)
// A (x): LDS-staged, 16 KB double buffer, depth-2 register prefetch.
// B (W): NO LDS — direct coalesced uint4 granule loads from L2-resident Wg.
// ---------------------------------------------------------------------------
#define GBM 64
#define GBK 64
#define GNKT (INPUT / GBK)  // 32

__global__ __launch_bounds__(256) void gemm_xw_f16(
    const float* __restrict__ x, const uint4* __restrict__ Wg,
    const float* __restrict__ b_ih, const float* __restrict__ b_hh,
    half_t* __restrict__ xw) {
  __shared__ uint4 sA[2][8][64];  // [buf][kc][m]  16 KB

  const int tid = threadIdx.x;
  const int lane = tid & 63;
  const int w = tid >> 6;
  const int wr = w >> 1, wc = w & 1;
  const int block_row = blockIdx.x * GBM;
  const int kcl = lane >> 4;
  const int l15 = lane & 15;

  const int xm = tid & 63, xkq = tid >> 6;  // x: row, k-quarter (16 f32)
  const float* xsrc = x + (size_t)(block_row + xm) * INPUT + xkq * 16;

  f32x4 acc[2][4];
#pragma unroll
  for (int rt = 0; rt < 2; ++rt)
#pragma unroll
    for (int ct = 0; ct < 4; ++ct) acc[rt][ct] = (f32x4)0.f;

  float bias_c[4];
#pragma unroll
  for (int ct = 0; ct < 4; ++ct) {
    const int col = wc * 64 + ct * 16 + l15;
    bias_c[ct] = b_ih[col] + b_hh[col];
  }

  float4 xva[4], xvb[4];
  uint4 br0[8], br1[8];

  auto XLOAD = [&](int kt, float4* xv) {
    const float4* xs = (const float4*)(xsrc + kt * GBK);
#pragma unroll
    for (int j = 0; j < 4; ++j) xv[j] = xs[j];
  };
  auto XWRITE = [&](int bf, const float4* xv) {
#pragma unroll
    for (int g = 0; g < 2; ++g) {
      uint4 q = {h2u(pkrtz(xv[2 * g].x, xv[2 * g].y)),
                 h2u(pkrtz(xv[2 * g].z, xv[2 * g].w)),
                 h2u(pkrtz(xv[2 * g + 1].x, xv[2 * g + 1].y)),
                 h2u(pkrtz(xv[2 * g + 1].z, xv[2 * g + 1].w))};
      sA[bf][xkq * 2 + g][xm] = q;
    }
  };
  auto BLOAD = [&](int kt, uint4* bb) {
#pragma unroll
    for (int kf = 0; kf < 2; ++kf)
#pragma unroll
      for (int ct = 0; ct < 4; ++ct)
        bb[kf * 4 + ct] =
            Wg[(size_t)(kt * 8 + kf * 4 + kcl) * 128 + wc * 64 + ct * 16 + l15];
  };
  auto COMPUTE = [&](int bf, const uint4* bb) {
    uint4 af[2][2];
#pragma unroll
    for (int kf = 0; kf < 2; ++kf)
#pragma unroll
      for (int rt = 0; rt < 2; ++rt)
        af[kf][rt] = sA[bf][kf * 4 + kcl][wr * 32 + rt * 16 + l15];
#pragma unroll
    for (int kf = 0; kf < 2; ++kf)
#pragma unroll
      for (int rt = 0; rt < 2; ++rt)
#pragma unroll
        for (int ct = 0; ct < 4; ++ct)
          acc[rt][ct] = __builtin_amdgcn_mfma_f32_16x16x32_f16(
              as_f16x8(af[kf][rt]), as_f16x8(bb[kf * 4 + ct]), acc[rt][ct], 0, 0, 0);
  };

  // prologue: x depth-2, B depth-1
  XLOAD(0, xva);
  XLOAD(1, xvb);
  BLOAD(0, br0);
  XWRITE(0, xva);
  __syncthreads();

#pragma unroll 1
  for (int kt = 0; kt < GNKT; kt += 2) {
    BLOAD(kt + 1, br1);
    if (kt + 2 < GNKT) XLOAD(kt + 2, xva);
    COMPUTE(0, br0);
    XWRITE(1, xvb);
    __syncthreads();
    if (kt + 2 < GNKT) BLOAD(kt + 2, br0);
    if (kt + 3 < GNKT) XLOAD(kt + 3, xvb);
    COMPUTE(1, br1);
    if (kt + 2 < GNKT) {
      XWRITE(0, xva);
      __syncthreads();
    }
  }

  // epilogue: C layout col = lane&15, row = (lane>>4)*4 + j
  const int rbase = block_row + wr * 32 + (lane >> 4) * 4;
#pragma unroll
  for (int rt = 0; rt < 2; ++rt)
#pragma unroll
    for (int ct = 0; ct < 4; ++ct) {
      const int col = wc * 64 + ct * 16 + l15;
#pragma unroll
      for (int j = 0; j < 4; ++j) {
        const int row = rbase + rt * 16 + j;
        xw[(size_t)row * HIDDEN + col] = (half_t)(acc[rt][ct][j] + bias_c[ct]);
      }
    }
}

// ---------------------------------------------------------------------------
// Recurrence via MFMA — EXACT R8 structure (measured 186 us; the R10 2+2
// split regressed to 211 us and is reverted). 4 blocks x 16 batch rows,
// 256 threads. A = W_hh resident in VGPRs, B = h-state in LDS [batch][k]
// f16 with XOR swizzle, C-input = xw (folds the add), D writes back as
// contiguous b64. One barrier per step; 2-step unroll.
// ---------------------------------------------------------------------------
__global__ __launch_bounds__(256) void rnn_rec_mfma(
    const half_t* __restrict__ xw, const unsigned int* __restrict__ Whh2,
    const float* __restrict__ W_fc, const float* __restrict__ b_fc,
    float* __restrict__ out) {
  const int blk = blockIdx.x;    // 0..3
  const int tid = threadIdx.x;
  const int lane = tid & 63;
  const int w = tid >> 6;        // wave 0..3 -> h' tiles 2w, 2w+1
  const int bl = lane & 15;      // batch-local 0..15
  const int g = lane >> 4;       // k-group 0..3
  const int swz = (bl & 7) << 4; // LDS XOR swizzle (bits 4..6)

  __shared__ half_t st[2][RB][HIDDEN];  // 8 KB state double buffer
  __shared__ float red[256];

  uint4 afr[2][4];
#pragma unroll
  for (int mi = 0; mi < 2; ++mi)
#pragma unroll
    for (int kt = 0; kt < 4; ++kt)
      afr[mi][kt] = *(const uint4*)(Whh2 + ((size_t)((2 * w + mi) * 16 + bl)) * 64 +
                                    kt * 16 + g * 4);

#pragma unroll
  for (int i = 0; i < 4; ++i) ((unsigned int*)st)[tid + 256 * i] = 0u;
  __syncthreads();

  const half_t* xb0 = xw + ((size_t)(blk * RB + bl) * TSTEPS) * HIDDEN + w * 32 + g * 4;
  const half_t* xb1 = xb0 + 16;

  float hh[2][4];

  auto STEP = [&](const half_t* stR, half_t* stW, ushort4 xc0, ushort4 xc1) {
    uint4 bfr[4];
#pragma unroll
    for (int kt = 0; kt < 4; ++kt) {
      const int off = (bl * 256 + kt * 64 + g * 16) ^ swz;
      bfr[kt] = *(const uint4*)((const char*)stR + off);
    }
    f32x4 a0, a1;
    a0[0] = h2f(xc0.x); a0[1] = h2f(xc0.y); a0[2] = h2f(xc0.z); a0[3] = h2f(xc0.w);
    a1[0] = h2f(xc1.x); a1[1] = h2f(xc1.y); a1[2] = h2f(xc1.z); a1[3] = h2f(xc1.w);
#pragma unroll
    for (int kt = 0; kt < 4; ++kt) {
      a0 = __builtin_amdgcn_mfma_f32_16x16x32_f16(as_f16x8(afr[0][kt]),
                                                  as_f16x8(bfr[kt]), a0, 0, 0, 0);
      a1 = __builtin_amdgcn_mfma_f32_16x16x32_f16(as_f16x8(afr[1][kt]),
                                                  as_f16x8(bfr[kt]), a1, 0, 0, 0);
    }
#pragma unroll
    for (int j = 0; j < 4; ++j) {
      hh[0][j] = tanh_fast(a0[j]);
      hh[1][j] = tanh_fast(a1[j]);
    }
    uint2 p0 = {h2u(pkrtz(hh[0][0], hh[0][1])), h2u(pkrtz(hh[0][2], hh[0][3]))};
    uint2 p1 = {h2u(pkrtz(hh[1][0], hh[1][1])), h2u(pkrtz(hh[1][2], hh[1][3]))};
    const int w0 = (bl * 256 + (2 * w + 0) * 32 + g * 8) ^ swz;
    const int w1 = (bl * 256 + (2 * w + 1) * 32 + g * 8) ^ swz;
    *(uint2*)((char*)stW + w0) = p0;
    *(uint2*)((char*)stW + w1) = p1;
    __syncthreads();
  };

  ushort4 xA0 = *(const ushort4*)(xb0);
  ushort4 xA1 = *(const ushort4*)(xb1);
  ushort4 xB0 = *(const ushort4*)(xb0 + HIDDEN);
  ushort4 xB1 = *(const ushort4*)(xb1 + HIDDEN);

  for (int t2 = 0; t2 < TSTEPS; t2 += 2) {
    ushort4 c0 = xA0, c1 = xA1;
    xA0 = *(const ushort4*)(xb0 + (size_t)(t2 + 2) * HIDDEN);
    xA1 = *(const ushort4*)(xb1 + (size_t)(t2 + 2) * HIDDEN);
    STEP(&st[0][0][0], &st[1][0][0], c0, c1);

    ushort4 d0 = xB0, d1 = xB1;
    xB0 = *(const ushort4*)(xb0 + (size_t)(t2 + 3) * HIDDEN);
    xB1 = *(const ushort4*)(xb1 + (size_t)(t2 + 3) * HIDDEN);
    STEP(&st[1][0][0], &st[0][0][0], d0, d1);
  }

  const float4 wf0 = *(const float4*)&W_fc[(2 * w + 0) * 16 + g * 4];
  const float4 wf1 = *(const float4*)&W_fc[(2 * w + 1) * 16 + g * 4];
  float partial = hh[0][0] * wf0.x + hh[0][1] * wf0.y + hh[0][2] * wf0.z +
                  hh[0][3] * wf0.w + hh[1][0] * wf1.x + hh[1][1] * wf1.y +
                  hh[1][2] * wf1.z + hh[1][3] * wf1.w;
  red[tid] = partial;
  __syncthreads();
  if (tid < RB) {
    float s = b_fc[0];
#pragma unroll
    for (int q = 0; q < 16; ++q) s += red[q * 16 + tid];
    out[blk * RB + tid] = s;
  }
}

extern "C" void kernel_launch(void* const* d_in, const int* in_sizes, int n_in,
                              void* d_out, int out_size, void* d_ws, size_t ws_size,
                              hipStream_t stream) {
  const float* x    = (const float*)d_in[0];
  const float* W_ih = (const float*)d_in[1];
  const float* W_hh = (const float*)d_in[2];
  const float* b_ih = (const float*)d_in[3];
  const float* b_hh = (const float*)d_in[4];
  const float* W_fc = (const float*)d_in[5];
  const float* b_fc = (const float*)d_in[6];

  char* ws = (char*)d_ws;
  half_t*       xwf16 = (half_t*)ws;                                     // 8 MB
  uint4*        Wg    = (uint4*)(ws + (8u << 20));                       // 512 KB
  unsigned int* Whh2  = (unsigned int*)(ws + (8u << 20) + (512u << 10)); // 32 KB

  prep_kernel<<<128, 256, 0, stream>>>(W_ih, W_hh, Wg, Whh2);
  gemm_xw_f16<<<(BATCH * TSTEPS) / GBM, 256, 0, stream>>>(x, Wg, b_ih, b_hh, xwf16);
  rnn_rec_mfma<<<BATCH / RB, 256, 0, stream>>>(xwf16, Whh2, W_fc, b_fc, (float*)d_out);
}